// Round 11
// baseline (504.492 us; speedup 1.0000x reference)
//
#include <hip/hip_runtime.h>
#include <hip/hip_bf16.h>

// VQ-VAE forward, B=64, F=16.  ALL I/O float32 (d_out = float*: decoded 4194304 f32, indices 262144 f32).
// ws layout: f1 (64 MiB) | f2 (16 MiB) | f3 (16 MiB) = 96 MiB.
// R11: tconv1_k rewritten as 2x2-quad-per-thread. Within a quad, output parity (dy,dx) is
//      compile-time -> weight indices wave-uniform -> SGPR s_load stream (R10 pattern), zero LDS.
// Ledger (R10): tconv1 75 | conv2 ~50-60 | res ~25-30 x4 | conv1 ~27 | tconv2 ~30-60 | vq ~15 = 322.6
// Lessons: no VGPR-clamp launch_bounds + unroll (R7); stage once barrier once (R8);
//          uniform weights -> SGPR, never per-FMA LDS reads (R10, R11).

// ---------------- conv1: 1->16, 256->128 ----------------
__global__ __launch_bounds__(256) void conv1_k(const float* __restrict__ x, const float* __restrict__ w,
                                               const float* __restrict__ bias, float* __restrict__ out) {
    int idx = blockIdx.x * 256 + threadIdx.x;   // 64*128*128
    int ox = idx & 127;
    int oy = (idx >> 7) & 127;
    int b  = idx >> 14;
    const float* xin = x + (size_t)b * 65536;
    float pv[16];
#pragma unroll
    for (int ky = 0; ky < 4; ++ky) {
        int iy = 2 * oy - 1 + ky;
#pragma unroll
        for (int kx = 0; kx < 4; ++kx) {
            int ix = 2 * ox - 1 + kx;
            pv[ky * 4 + kx] = (iy >= 0 && iy < 256 && ix >= 0 && ix < 256)
                                  ? xin[iy * 256 + ix] : 0.f;
        }
    }
    float* o = out + (size_t)b * (16 * 16384) + oy * 128 + ox;
#pragma unroll
    for (int oc = 0; oc < 16; ++oc) {
        float acc = bias[oc];                       // uniform -> SGPR
#pragma unroll
        for (int k = 0; k < 16; ++k) acc = fmaf(pv[k], w[oc * 16 + k], acc);   // uniform -> SGPR
        o[oc * 16384] = fmaxf(acc, 0.f);
    }
}

// ---------------- conv2: 16->16, 128->64 ----------------
__global__ __launch_bounds__(256) void conv2_k(const float* __restrict__ in, const float* __restrict__ w,
                                               const float* __restrict__ bias, float* __restrict__ out) {
    int idx = blockIdx.x * 256 + threadIdx.x;   // 64*64*64
    int ox = idx & 63;
    int oy = (idx >> 6) & 63;
    int b  = idx >> 12;
    const float* xin = in + (size_t)b * (16 * 16384);
    float acc[16];
#pragma unroll
    for (int oc = 0; oc < 16; ++oc) acc[oc] = bias[oc];     // uniform
    for (int ic = 0; ic < 16; ++ic) {
        const float* xc = xin + ic * 16384;
        float p[16];
#pragma unroll
        for (int ky = 0; ky < 4; ++ky) {
            int iy = 2 * oy - 1 + ky;
#pragma unroll
            for (int kx = 0; kx < 4; ++kx) {
                int ix = 2 * ox - 1 + kx;
                p[ky * 4 + kx] = (iy >= 0 && iy < 128 && ix >= 0 && ix < 128)
                                     ? xc[iy * 128 + ix] : 0.f;
            }
        }
        const float* wp0 = w + ic * 16;             // (oc,ic,4,4): oc stride 256
#pragma unroll
        for (int oc = 0; oc < 16; ++oc) {
            const float* wp = wp0 + oc * 256;       // uniform
#pragma unroll
            for (int k = 0; k < 16; ++k) acc[oc] = fmaf(p[k], wp[k], acc[oc]);
        }
    }
    float* o = out + (size_t)b * (16 * 4096) + oy * 64 + ox;
#pragma unroll
    for (int oc = 0; oc < 16; ++oc) o[oc * 4096] = fmaxf(acc[oc], 0.f);
}

// ---------------- residual block: out = in + relu(conv3x3(in)), (64,16,64,64) ----------------
__global__ __launch_bounds__(256) void res_k(const float* __restrict__ in, const float* __restrict__ w,
                                             const float* __restrict__ bias, float* __restrict__ out) {
    int b    = blockIdx.x >> 3;            // image
    int ty   = (blockIdx.x & 7) * 8;       // tile row origin (8 rows/block)
    int row  = threadIdx.x >> 5;           // 0..7
    int col2 = threadIdx.x & 31;           // 0..31
    int oy   = ty + row;
    int ox0  = col2 * 2;
    const float* xin = in + (size_t)b * 65536;
    float acc0[16], acc1[16];
#pragma unroll
    for (int oc = 0; oc < 16; ++oc) { acc0[oc] = bias[oc]; acc1[oc] = bias[oc]; }
    for (int ic = 0; ic < 16; ++ic) {
        const float* xc = xin + ic * 4096;
        float p[3][4];
#pragma unroll
        for (int r = 0; r < 3; ++r) {
            int iy = oy - 1 + r;
            bool yok = (iy >= 0 && iy < 64);
#pragma unroll
            for (int c = 0; c < 4; ++c) {
                int ix = ox0 - 1 + c;
                p[r][c] = (yok && ix >= 0 && ix < 64) ? xc[iy * 64 + ix] : 0.f;
            }
        }
        const float* wp0 = w + ic * 9;              // (oc,ic,3,3): oc stride 144
#pragma unroll
        for (int oc = 0; oc < 16; ++oc) {
            const float* wp = wp0 + oc * 144;       // uniform
#pragma unroll
            for (int r = 0; r < 3; ++r) {
#pragma unroll
                for (int k = 0; k < 3; ++k) {
                    float wv = wp[r * 3 + k];
                    acc0[oc] = fmaf(p[r][k],     wv, acc0[oc]);
                    acc1[oc] = fmaf(p[r][k + 1], wv, acc1[oc]);
                }
            }
        }
    }
    float* o        = out + (size_t)b * 65536 + oy * 64 + ox0;
    const float* rr = xin + oy * 64 + ox0;
#pragma unroll
    for (int oc = 0; oc < 16; ++oc) {
        float2 rv = *(const float2*)(rr + oc * 4096);
        float2 ov;
        ov.x = rv.x + fmaxf(acc0[oc], 0.f);
        ov.y = rv.y + fmaxf(acc1[oc], 0.f);
        *(float2*)(o + oc * 4096) = ov;
    }
}

// ---------------- VQ: rows of 16 contiguous floats (raw NCHW flatten), K=64 ----------------
__global__ __launch_bounds__(256) void vq_k(const float* __restrict__ h, const float* __restrict__ cb,
                                            float* __restrict__ q, float* __restrict__ idx_out) {
    __shared__ float cbs[1024];  // 64 x 16
    __shared__ float cn[64];
    for (int i = threadIdx.x; i < 1024; i += 256) cbs[i] = cb[i];
    __syncthreads();
    if (threadIdx.x < 64) {
        float s = 0.f;
#pragma unroll
        for (int d = 0; d < 16; ++d) { float v = cbs[threadIdx.x * 16 + d]; s = fmaf(v, v, s); }
        cn[threadIdx.x] = s;
    }
    __syncthreads();
    int r = blockIdx.x * 256 + threadIdx.x;   // 262144 rows
    float f[16];
    const float4* hp = (const float4*)(h + (size_t)r * 16);
#pragma unroll
    for (int j = 0; j < 4; ++j) {
        float4 v = hp[j];
        f[j * 4 + 0] = v.x; f[j * 4 + 1] = v.y; f[j * 4 + 2] = v.z; f[j * 4 + 3] = v.w;
    }
    float best = 3.4e38f;
    int bi = 0;
    for (int k = 0; k < 64; ++k) {
        float dot = 0.f;
#pragma unroll
        for (int d = 0; d < 16; ++d) dot = fmaf(f[d], cbs[k * 16 + d], dot);
        float dist = cn[k] - 2.f * dot;   // +||f||^2 is per-row constant, argmin-invariant
        if (dist < best) { best = dist; bi = k; }
    }
    float4* qp = (float4*)(q + (size_t)r * 16);
    const float4* cp = (const float4*)(cbs + bi * 16);
#pragma unroll
    for (int j = 0; j < 4; ++j) qp[j] = cp[j];
    idx_out[r] = (float)bi;
}

// ---------------- tconv1: ConvTranspose2d 16->16, k4 s2 p1, 64->128, relu ----------------
// 2x2 output quad per thread: parity (dy,dx) compile-time -> ky=(1-dy)+2a, kx=(1-dx)+2c literals
// -> weight addr wave-uniform -> SGPR. 3x3x16 input neighborhood, coalesced. CHANNEL-LAST out.
__global__ __launch_bounds__(256) void tconv1_k(const float* __restrict__ in,
                                                const float* __restrict__ w1, const float* __restrict__ b1,
                                                float* __restrict__ out) {
    int idx = blockIdx.x * 256 + threadIdx.x;   // 64 img * 64*64 quads
    int v = idx & 63;                            // quad col  (output cols 2v,2v+1)
    int u = (idx >> 6) & 63;                     // quad row
    int b = idx >> 12;
    const float* xin = in + (size_t)b * 65536;   // (16,64,64) channel-first

    float acc[2][2][16];
#pragma unroll
    for (int dy = 0; dy < 2; ++dy)
#pragma unroll
        for (int dx = 0; dx < 2; ++dx)
#pragma unroll
            for (int oc = 0; oc < 16; ++oc) acc[dy][dx][oc] = b1[oc];   // uniform

    for (int ic = 0; ic < 16; ++ic) {
        const float* xc = xin + ic * 4096;
        float p[3][3];
#pragma unroll
        for (int r = 0; r < 3; ++r) {
            int jy = u - 1 + r;
            bool yok = (jy >= 0 && jy < 64);
#pragma unroll
            for (int c = 0; c < 3; ++c) {
                int jx = v - 1 + c;
                p[r][c] = (yok && jx >= 0 && jx < 64) ? xc[jy * 64 + jx] : 0.f;
            }
        }
        const float* wic = w1 + ic * 256;            // (ic,oc,4,4)
#pragma unroll
        for (int dy = 0; dy < 2; ++dy) {
#pragma unroll
            for (int dx = 0; dx < 2; ++dx) {
#pragma unroll
                for (int a = 0; a < 2; ++a) {
                    int ky = (1 - dy) + 2 * a;       // literal
                    int ry = 1 + dy - a;             // p row
#pragma unroll
                    for (int c = 0; c < 2; ++c) {
                        int kx = (1 - dx) + 2 * c;   // literal
                        int rx = 1 + dx - c;
                        float pv = p[ry][rx];
#pragma unroll
                        for (int oc = 0; oc < 16; ++oc)
                            acc[dy][dx][oc] = fmaf(pv, wic[oc * 16 + ky * 4 + kx], acc[dy][dx][oc]);
                    }
                }
            }
        }
    }
    // stores: channel-last (b,128,128,16), relu
#pragma unroll
    for (int dy = 0; dy < 2; ++dy) {
#pragma unroll
        for (int dx = 0; dx < 2; ++dx) {
            int my = 2 * u + dy, mx = 2 * v + dx;
            float4* o = (float4*)(out + (((size_t)b * 16384) + my * 128 + mx) * 16);
#pragma unroll
            for (int j = 0; j < 4; ++j) {
                float4 t;
                t.x = fmaxf(acc[dy][dx][j * 4 + 0], 0.f);
                t.y = fmaxf(acc[dy][dx][j * 4 + 1], 0.f);
                t.z = fmaxf(acc[dy][dx][j * 4 + 2], 0.f);
                t.w = fmaxf(acc[dy][dx][j * 4 + 3], 0.f);
                o[j] = t;
            }
        }
    }
}

// ---------------- tconv2: ConvTranspose2d 16->1, k4 s2 p1, 128->256 ----------------
// 32x32 output tile/block; stage 18x18x16 channel-last slab into LDS [324][20]; float4 LDS reads.
#define P2 20
__global__ __launch_bounds__(256) void tconv2_k(const float* __restrict__ f1,
                                                const float* __restrict__ w2, const float* __restrict__ b2,
                                                float* __restrict__ out) {
    __shared__ float s1[324 * P2];       // [pixel(18x18)][16 ch + pad4]
    __shared__ float ws2[256];           // (ic,1,4,4)
    __shared__ float b2s;
    if (threadIdx.x < 256) ws2[threadIdx.x] = w2[threadIdx.x];
    if (threadIdx.x == 0) b2s = b2[0];

    int tile = blockIdx.x & 63;
    int b    = blockIdx.x >> 6;
    int Y0 = (tile >> 3) * 32;           // final-out tile origin (256x256)
    int X0 = (tile & 7) * 32;
    int m0 = (Y0 >> 1) - 1;              // halo origin in tconv1-out coords [-1,128]
    int n0 = (X0 >> 1) - 1;
    const float* fb = f1 + (size_t)b * 262144;   // (128,128,16) channel-last

    // stage 324 px x 16 ch (coalesced global reads; LDS writes <=2-way)
    for (int i = threadIdx.x; i < 5184; i += 256) {
        int p  = i >> 4;
        int ic = i & 15;
        int my = m0 + p / 18;
        int mx = n0 + p % 18;
        float v = 0.f;
        if (my >= 0 && my < 128 && mx >= 0 && mx < 128)
            v = fb[((size_t)(my * 128 + mx)) * 16 + ic];
        s1[p * P2 + ic] = v;
    }
    __syncthreads();

    // each thread: 4 output px (same lx, ly0+8r) -> same (kyb,kxb); preload 64 weights to regs
    int ly0 = threadIdx.x >> 5;          // 0..7
    int lx  = threadIdx.x & 31;
    int gx  = X0 + lx;
    int kyb = (Y0 + ly0 + 1) & 1;
    int kxb = (gx + 1) & 1;
    float wr[2][2][16];
#pragma unroll
    for (int a = 0; a < 2; ++a) {
#pragma unroll
        for (int c = 0; c < 2; ++c) {
            int ky = kyb + 2 * a, kx = kxb + 2 * c;
#pragma unroll
            for (int ic = 0; ic < 16; ++ic)
                wr[a][c][ic] = ws2[ic * 16 + ky * 4 + kx];
        }
    }
    int sx[2];
#pragma unroll
    for (int c = 0; c < 2; ++c) sx[c] = ((gx + 1 - (kxb + 2 * c)) >> 1) - n0;

#pragma unroll
    for (int r = 0; r < 4; ++r) {
        int gy = Y0 + ly0 + 8 * r;
        float acc = b2s;
#pragma unroll
        for (int a = 0; a < 2; ++a) {
            int sy = ((gy + 1 - (kyb + 2 * a)) >> 1) - m0;
#pragma unroll
            for (int c = 0; c < 2; ++c) {
                const float4* sp4 = (const float4*)&s1[(sy * 18 + sx[c]) * P2];
#pragma unroll
                for (int j = 0; j < 4; ++j) {
                    float4 v = sp4[j];
                    acc = fmaf(v.x, wr[a][c][j * 4 + 0], acc);
                    acc = fmaf(v.y, wr[a][c][j * 4 + 1], acc);
                    acc = fmaf(v.z, wr[a][c][j * 4 + 2], acc);
                    acc = fmaf(v.w, wr[a][c][j * 4 + 3], acc);
                }
            }
        }
        out[(size_t)b * 65536 + gy * 256 + gx] = acc;
    }
}

extern "C" void kernel_launch(void* const* d_in, const int* in_sizes, int n_in,
                              void* d_out, int out_size, void* d_ws, size_t ws_size,
                              hipStream_t stream) {
    const float* x    = (const float*)d_in[0];
    const float* c1w  = (const float*)d_in[1];
    const float* c1b  = (const float*)d_in[2];
    const float* c2w  = (const float*)d_in[3];
    const float* c2b  = (const float*)d_in[4];
    const float* er1w = (const float*)d_in[5];
    const float* er1b = (const float*)d_in[6];
    const float* er2w = (const float*)d_in[7];
    const float* er2b = (const float*)d_in[8];
    const float* cb   = (const float*)d_in[9];
    const float* dr1w = (const float*)d_in[10];
    const float* dr1b = (const float*)d_in[11];
    const float* dr2w = (const float*)d_in[12];
    const float* dr2b = (const float*)d_in[13];
    const float* t1w  = (const float*)d_in[14];
    const float* t1b  = (const float*)d_in[15];
    const float* t2w  = (const float*)d_in[16];
    const float* t2b  = (const float*)d_in[17];

    float* f1 = (float*)d_ws;                                // 64 MiB: dec ch-last
    float* f2 = (float*)((char*)d_ws + 67108864);            // (64,16,64,64)
    float* f3 = (float*)((char*)d_ws + 67108864 + 16777216); // (64,16,64,64)

    float* out     = (float*)d_out;                          // decoded: 4,194,304 f32
    float* idx_out = out + 4194304;                          // indices: 262,144 f32

    conv1_k <<<4096, 256, 0, stream>>>(x, c1w, c1b, f1);
    conv2_k <<<1024, 256, 0, stream>>>(f1, c2w, c2b, f2);
    res_k   <<< 512, 256, 0, stream>>>(f2, er1w, er1b, f3);  // er1
    res_k   <<< 512, 256, 0, stream>>>(f3, er2w, er2b, f2);  // er2
    vq_k    <<<1024, 256, 0, stream>>>(f2, cb, f3, idx_out); // quantized -> f3
    res_k   <<< 512, 256, 0, stream>>>(f3, dr1w, dr1b, f2);  // dr1
    res_k   <<< 512, 256, 0, stream>>>(f2, dr2w, dr2b, f3);  // dr2
    tconv1_k<<<1024, 256, 0, stream>>>(f3, t1w, t1b, f1);
    tconv2_k<<<4096, 256, 0, stream>>>(f1, t2w, t2b, out);
}

// Round 12
// 313.688 us; speedup vs baseline: 1.6083x; 1.6083x over previous
//
#include <hip/hip_runtime.h>
#include <hip/hip_bf16.h>

// VQ-VAE forward, B=64, F=16.  ALL I/O float32 (d_out = float*: decoded 4194304 f32, indices 262144 f32).
// ws layout: f1 (64 MiB) | f2 (16 MiB) | f3 (16 MiB) = 96 MiB.
// R12: tconv1_k = row-pair structure. dy compile-time outer, acc[2][16] (32 regs, no spill),
//      parity-literal weight indices -> SGPR stream; coalesced 128B/lane channel-last stores.
// Ledger (R10/R11): conv1 ~27 | conv2 ~50-60 | res ~25-30 x4 | vq ~15 | tconv2 ~30-40 | rest 237.
// Lessons: no VGPR-clamp launch_bounds + big unroll (R7); stage once barrier once (R8);
//          uniform weights -> SGPR not LDS (R10); accumulator arrays <= ~32 or allocator spills (R11).

// ---------------- conv1: 1->16, 256->128 ----------------
__global__ __launch_bounds__(256) void conv1_k(const float* __restrict__ x, const float* __restrict__ w,
                                               const float* __restrict__ bias, float* __restrict__ out) {
    int idx = blockIdx.x * 256 + threadIdx.x;   // 64*128*128
    int ox = idx & 127;
    int oy = (idx >> 7) & 127;
    int b  = idx >> 14;
    const float* xin = x + (size_t)b * 65536;
    float pv[16];
#pragma unroll
    for (int ky = 0; ky < 4; ++ky) {
        int iy = 2 * oy - 1 + ky;
#pragma unroll
        for (int kx = 0; kx < 4; ++kx) {
            int ix = 2 * ox - 1 + kx;
            pv[ky * 4 + kx] = (iy >= 0 && iy < 256 && ix >= 0 && ix < 256)
                                  ? xin[iy * 256 + ix] : 0.f;
        }
    }
    float* o = out + (size_t)b * (16 * 16384) + oy * 128 + ox;
#pragma unroll
    for (int oc = 0; oc < 16; ++oc) {
        float acc = bias[oc];                       // uniform -> SGPR
#pragma unroll
        for (int k = 0; k < 16; ++k) acc = fmaf(pv[k], w[oc * 16 + k], acc);   // uniform -> SGPR
        o[oc * 16384] = fmaxf(acc, 0.f);
    }
}

// ---------------- conv2: 16->16, 128->64 ----------------
__global__ __launch_bounds__(256) void conv2_k(const float* __restrict__ in, const float* __restrict__ w,
                                               const float* __restrict__ bias, float* __restrict__ out) {
    int idx = blockIdx.x * 256 + threadIdx.x;   // 64*64*64
    int ox = idx & 63;
    int oy = (idx >> 6) & 63;
    int b  = idx >> 12;
    const float* xin = in + (size_t)b * (16 * 16384);
    float acc[16];
#pragma unroll
    for (int oc = 0; oc < 16; ++oc) acc[oc] = bias[oc];     // uniform
    for (int ic = 0; ic < 16; ++ic) {
        const float* xc = xin + ic * 16384;
        float p[16];
#pragma unroll
        for (int ky = 0; ky < 4; ++ky) {
            int iy = 2 * oy - 1 + ky;
#pragma unroll
            for (int kx = 0; kx < 4; ++kx) {
                int ix = 2 * ox - 1 + kx;
                p[ky * 4 + kx] = (iy >= 0 && iy < 128 && ix >= 0 && ix < 128)
                                     ? xc[iy * 128 + ix] : 0.f;
            }
        }
        const float* wp0 = w + ic * 16;             // (oc,ic,4,4): oc stride 256
#pragma unroll
        for (int oc = 0; oc < 16; ++oc) {
            const float* wp = wp0 + oc * 256;       // uniform
#pragma unroll
            for (int k = 0; k < 16; ++k) acc[oc] = fmaf(p[k], wp[k], acc[oc]);
        }
    }
    float* o = out + (size_t)b * (16 * 4096) + oy * 64 + ox;
#pragma unroll
    for (int oc = 0; oc < 16; ++oc) o[oc * 4096] = fmaxf(acc[oc], 0.f);
}

// ---------------- residual block: out = in + relu(conv3x3(in)), (64,16,64,64) ----------------
__global__ __launch_bounds__(256) void res_k(const float* __restrict__ in, const float* __restrict__ w,
                                             const float* __restrict__ bias, float* __restrict__ out) {
    int b    = blockIdx.x >> 3;            // image
    int ty   = (blockIdx.x & 7) * 8;       // tile row origin (8 rows/block)
    int row  = threadIdx.x >> 5;           // 0..7
    int col2 = threadIdx.x & 31;           // 0..31
    int oy   = ty + row;
    int ox0  = col2 * 2;
    const float* xin = in + (size_t)b * 65536;
    float acc0[16], acc1[16];
#pragma unroll
    for (int oc = 0; oc < 16; ++oc) { acc0[oc] = bias[oc]; acc1[oc] = bias[oc]; }
    for (int ic = 0; ic < 16; ++ic) {
        const float* xc = xin + ic * 4096;
        float p[3][4];
#pragma unroll
        for (int r = 0; r < 3; ++r) {
            int iy = oy - 1 + r;
            bool yok = (iy >= 0 && iy < 64);
#pragma unroll
            for (int c = 0; c < 4; ++c) {
                int ix = ox0 - 1 + c;
                p[r][c] = (yok && ix >= 0 && ix < 64) ? xc[iy * 64 + ix] : 0.f;
            }
        }
        const float* wp0 = w + ic * 9;              // (oc,ic,3,3): oc stride 144
#pragma unroll
        for (int oc = 0; oc < 16; ++oc) {
            const float* wp = wp0 + oc * 144;       // uniform
#pragma unroll
            for (int r = 0; r < 3; ++r) {
#pragma unroll
                for (int k = 0; k < 3; ++k) {
                    float wv = wp[r * 3 + k];
                    acc0[oc] = fmaf(p[r][k],     wv, acc0[oc]);
                    acc1[oc] = fmaf(p[r][k + 1], wv, acc1[oc]);
                }
            }
        }
    }
    float* o        = out + (size_t)b * 65536 + oy * 64 + ox0;
    const float* rr = xin + oy * 64 + ox0;
#pragma unroll
    for (int oc = 0; oc < 16; ++oc) {
        float2 rv = *(const float2*)(rr + oc * 4096);
        float2 ov;
        ov.x = rv.x + fmaxf(acc0[oc], 0.f);
        ov.y = rv.y + fmaxf(acc1[oc], 0.f);
        *(float2*)(o + oc * 4096) = ov;
    }
}

// ---------------- VQ: rows of 16 contiguous floats (raw NCHW flatten), K=64 ----------------
__global__ __launch_bounds__(256) void vq_k(const float* __restrict__ h, const float* __restrict__ cb,
                                            float* __restrict__ q, float* __restrict__ idx_out) {
    __shared__ float cbs[1024];  // 64 x 16
    __shared__ float cn[64];
    for (int i = threadIdx.x; i < 1024; i += 256) cbs[i] = cb[i];
    __syncthreads();
    if (threadIdx.x < 64) {
        float s = 0.f;
#pragma unroll
        for (int d = 0; d < 16; ++d) { float v = cbs[threadIdx.x * 16 + d]; s = fmaf(v, v, s); }
        cn[threadIdx.x] = s;
    }
    __syncthreads();
    int r = blockIdx.x * 256 + threadIdx.x;   // 262144 rows
    float f[16];
    const float4* hp = (const float4*)(h + (size_t)r * 16);
#pragma unroll
    for (int j = 0; j < 4; ++j) {
        float4 v = hp[j];
        f[j * 4 + 0] = v.x; f[j * 4 + 1] = v.y; f[j * 4 + 2] = v.z; f[j * 4 + 3] = v.w;
    }
    float best = 3.4e38f;
    int bi = 0;
    for (int k = 0; k < 64; ++k) {
        float dot = 0.f;
#pragma unroll
        for (int d = 0; d < 16; ++d) dot = fmaf(f[d], cbs[k * 16 + d], dot);
        float dist = cn[k] - 2.f * dot;   // +||f||^2 is per-row constant, argmin-invariant
        if (dist < best) { best = dist; bi = k; }
    }
    float4* qp = (float4*)(q + (size_t)r * 16);
    const float4* cp = (const float4*)(cbs + bi * 16);
#pragma unroll
    for (int j = 0; j < 4; ++j) qp[j] = cp[j];
    idx_out[r] = (float)bi;
}

// ---------------- tconv1: ConvTranspose2d 16->16, k4 s2 p1, 64->128, relu ----------------
// Row-pair: outer dy (compile-time), acc[2][16] covers (2u+dy, 2v) and (2u+dy, 2v+1).
// Weight indices literal per (dy,dx,a,c) -> wave-uniform -> SGPR. Zero LDS. CHANNEL-LAST out,
// per-dy store = 32 contiguous floats/lane (fully coalesced).
__global__ __launch_bounds__(256) void tconv1_k(const float* __restrict__ in,
                                                const float* __restrict__ w1, const float* __restrict__ b1,
                                                float* __restrict__ out) {
    int idx = blockIdx.x * 256 + threadIdx.x;   // 64 img * 64*64 quads
    int v = idx & 63;                            // quad col (output cols 2v, 2v+1)
    int u = (idx >> 6) & 63;                     // quad row
    int b = idx >> 12;
    const float* xin = in + (size_t)b * 65536;   // (16,64,64) channel-first

#pragma unroll
    for (int dy = 0; dy < 2; ++dy) {
        float acc[2][16];                        // [dx][oc] -- 32 regs
#pragma unroll
        for (int dx = 0; dx < 2; ++dx)
#pragma unroll
            for (int oc = 0; oc < 16; ++oc) acc[dx][oc] = b1[oc];   // uniform

        for (int ic = 0; ic < 16; ++ic) {
            const float* xc = xin + ic * 4096;
            // needed input window: rows u+dy-1 .. u+dy, cols v-1 .. v+1
            float pv[2][3];
#pragma unroll
            for (int r = 0; r < 2; ++r) {
                int jy = u + dy - 1 + r;
                bool yok = (jy >= 0 && jy < 64);
#pragma unroll
                for (int c3 = 0; c3 < 3; ++c3) {
                    int jx = v - 1 + c3;
                    pv[r][c3] = (yok && jx >= 0 && jx < 64) ? xc[jy * 64 + jx] : 0.f;
                }
            }
            const float* wic = w1 + ic * 256;    // (ic,oc,4,4)
#pragma unroll
            for (int dx = 0; dx < 2; ++dx) {
#pragma unroll
                for (int a = 0; a < 2; ++a) {
                    int ky = (1 - dy) + 2 * a;   // literal
                    int r  = 1 - a;              // pv row for jy = u+dy-a
#pragma unroll
                    for (int c = 0; c < 2; ++c) {
                        int kx = (1 - dx) + 2 * c;   // literal
                        int c3 = dx - c + 1;         // pv col for jx = v+dx-c
                        float p = pv[r][c3];
#pragma unroll
                        for (int oc = 0; oc < 16; ++oc)
                            acc[dx][oc] = fmaf(p, wic[oc * 16 + ky * 4 + kx], acc[dx][oc]);
                    }
                }
            }
        }
        // store row my=2u+dy, pixels mx=2v and 2v+1: 32 contiguous floats (channel-last)
        int my = 2 * u + dy;
        float4* o = (float4*)(out + (((size_t)b * 16384) + my * 128 + 2 * v) * 16);
#pragma unroll
        for (int dx = 0; dx < 2; ++dx) {
#pragma unroll
            for (int j = 0; j < 4; ++j) {
                float4 t;
                t.x = fmaxf(acc[dx][j * 4 + 0], 0.f);
                t.y = fmaxf(acc[dx][j * 4 + 1], 0.f);
                t.z = fmaxf(acc[dx][j * 4 + 2], 0.f);
                t.w = fmaxf(acc[dx][j * 4 + 3], 0.f);
                o[dx * 4 + j] = t;
            }
        }
    }
}

// ---------------- tconv2: ConvTranspose2d 16->1, k4 s2 p1, 128->256 ----------------
// 32x32 output tile/block; stage 18x18x16 channel-last slab into LDS [324][20]; float4 LDS reads.
#define P2 20
__global__ __launch_bounds__(256) void tconv2_k(const float* __restrict__ f1,
                                                const float* __restrict__ w2, const float* __restrict__ b2,
                                                float* __restrict__ out) {
    __shared__ float s1[324 * P2];       // [pixel(18x18)][16 ch + pad4]
    __shared__ float ws2[256];           // (ic,1,4,4)
    __shared__ float b2s;
    if (threadIdx.x < 256) ws2[threadIdx.x] = w2[threadIdx.x];
    if (threadIdx.x == 0) b2s = b2[0];

    int tile = blockIdx.x & 63;
    int b    = blockIdx.x >> 6;
    int Y0 = (tile >> 3) * 32;           // final-out tile origin (256x256)
    int X0 = (tile & 7) * 32;
    int m0 = (Y0 >> 1) - 1;              // halo origin in tconv1-out coords [-1,128]
    int n0 = (X0 >> 1) - 1;
    const float* fb = f1 + (size_t)b * 262144;   // (128,128,16) channel-last

    // stage 324 px x 16 ch (coalesced global reads; LDS writes <=2-way)
    for (int i = threadIdx.x; i < 5184; i += 256) {
        int p  = i >> 4;
        int ic = i & 15;
        int my = m0 + p / 18;
        int mx = n0 + p % 18;
        float v = 0.f;
        if (my >= 0 && my < 128 && mx >= 0 && mx < 128)
            v = fb[((size_t)(my * 128 + mx)) * 16 + ic];
        s1[p * P2 + ic] = v;
    }
    __syncthreads();

    // each thread: 4 output px (same lx, ly0+8r) -> same (kyb,kxb); preload 64 weights to regs
    int ly0 = threadIdx.x >> 5;          // 0..7
    int lx  = threadIdx.x & 31;
    int gx  = X0 + lx;
    int kyb = (Y0 + ly0 + 1) & 1;
    int kxb = (gx + 1) & 1;
    float wr[2][2][16];
#pragma unroll
    for (int a = 0; a < 2; ++a) {
#pragma unroll
        for (int c = 0; c < 2; ++c) {
            int ky = kyb + 2 * a, kx = kxb + 2 * c;
#pragma unroll
            for (int ic = 0; ic < 16; ++ic)
                wr[a][c][ic] = ws2[ic * 16 + ky * 4 + kx];
        }
    }
    int sx[2];
#pragma unroll
    for (int c = 0; c < 2; ++c) sx[c] = ((gx + 1 - (kxb + 2 * c)) >> 1) - n0;

#pragma unroll
    for (int r = 0; r < 4; ++r) {
        int gy = Y0 + ly0 + 8 * r;
        float acc = b2s;
#pragma unroll
        for (int a = 0; a < 2; ++a) {
            int sy = ((gy + 1 - (kyb + 2 * a)) >> 1) - m0;
#pragma unroll
            for (int c = 0; c < 2; ++c) {
                const float4* sp4 = (const float4*)&s1[(sy * 18 + sx[c]) * P2];
#pragma unroll
                for (int j = 0; j < 4; ++j) {
                    float4 v = sp4[j];
                    acc = fmaf(v.x, wr[a][c][j * 4 + 0], acc);
                    acc = fmaf(v.y, wr[a][c][j * 4 + 1], acc);
                    acc = fmaf(v.z, wr[a][c][j * 4 + 2], acc);
                    acc = fmaf(v.w, wr[a][c][j * 4 + 3], acc);
                }
            }
        }
        out[(size_t)b * 65536 + gy * 256 + gx] = acc;
    }
}

extern "C" void kernel_launch(void* const* d_in, const int* in_sizes, int n_in,
                              void* d_out, int out_size, void* d_ws, size_t ws_size,
                              hipStream_t stream) {
    const float* x    = (const float*)d_in[0];
    const float* c1w  = (const float*)d_in[1];
    const float* c1b  = (const float*)d_in[2];
    const float* c2w  = (const float*)d_in[3];
    const float* c2b  = (const float*)d_in[4];
    const float* er1w = (const float*)d_in[5];
    const float* er1b = (const float*)d_in[6];
    const float* er2w = (const float*)d_in[7];
    const float* er2b = (const float*)d_in[8];
    const float* cb   = (const float*)d_in[9];
    const float* dr1w = (const float*)d_in[10];
    const float* dr1b = (const float*)d_in[11];
    const float* dr2w = (const float*)d_in[12];
    const float* dr2b = (const float*)d_in[13];
    const float* t1w  = (const float*)d_in[14];
    const float* t1b  = (const float*)d_in[15];
    const float* t2w  = (const float*)d_in[16];
    const float* t2b  = (const float*)d_in[17];

    float* f1 = (float*)d_ws;                                // 64 MiB: dec ch-last
    float* f2 = (float*)((char*)d_ws + 67108864);            // (64,16,64,64)
    float* f3 = (float*)((char*)d_ws + 67108864 + 16777216); // (64,16,64,64)

    float* out     = (float*)d_out;                          // decoded: 4,194,304 f32
    float* idx_out = out + 4194304;                          // indices: 262,144 f32

    conv1_k <<<4096, 256, 0, stream>>>(x, c1w, c1b, f1);
    conv2_k <<<1024, 256, 0, stream>>>(f1, c2w, c2b, f2);
    res_k   <<< 512, 256, 0, stream>>>(f2, er1w, er1b, f3);  // er1
    res_k   <<< 512, 256, 0, stream>>>(f3, er2w, er2b, f2);  // er2
    vq_k    <<<1024, 256, 0, stream>>>(f2, cb, f3, idx_out); // quantized -> f3
    res_k   <<< 512, 256, 0, stream>>>(f3, dr1w, dr1b, f2);  // dr1
    res_k   <<< 512, 256, 0, stream>>>(f2, dr2w, dr2b, f3);  // dr2
    tconv1_k<<<1024, 256, 0, stream>>>(f3, t1w, t1b, f1);
    tconv2_k<<<4096, 256, 0, stream>>>(f1, t2w, t2b, out);
}

// Round 13
// 312.937 us; speedup vs baseline: 1.6121x; 1.0024x over previous
//
#include <hip/hip_runtime.h>
#include <hip/hip_bf16.h>

// VQ-VAE forward, B=64, F=16.  ALL I/O float32 (d_out = float*: decoded 4194304 f32, indices 262144 f32).
// ws layout: f1 (64 MiB) | f2 (16 MiB) | f3 (16 MiB) = 96 MiB.
// R13: __launch_bounds__(256, 2) on conv2/res/tconv1 to raise VGPR budget (allocator was
//      spilling acc arrays at VGPR=28/32 chasing 8-waves/SIMD; grid only provides 4).
// Lessons: pressure must fit the budget you request (R7); stage once barrier once (R8);
//          uniform weights -> SGPR not LDS (R10); acc arrays spill unless budget raised (R11/R12/R13).

// ---------------- conv1: 1->16, 256->128 ----------------
__global__ __launch_bounds__(256) void conv1_k(const float* __restrict__ x, const float* __restrict__ w,
                                               const float* __restrict__ bias, float* __restrict__ out) {
    int idx = blockIdx.x * 256 + threadIdx.x;   // 64*128*128
    int ox = idx & 127;
    int oy = (idx >> 7) & 127;
    int b  = idx >> 14;
    const float* xin = x + (size_t)b * 65536;
    float pv[16];
#pragma unroll
    for (int ky = 0; ky < 4; ++ky) {
        int iy = 2 * oy - 1 + ky;
#pragma unroll
        for (int kx = 0; kx < 4; ++kx) {
            int ix = 2 * ox - 1 + kx;
            pv[ky * 4 + kx] = (iy >= 0 && iy < 256 && ix >= 0 && ix < 256)
                                  ? xin[iy * 256 + ix] : 0.f;
        }
    }
    float* o = out + (size_t)b * (16 * 16384) + oy * 128 + ox;
#pragma unroll
    for (int oc = 0; oc < 16; ++oc) {
        float acc = bias[oc];                       // uniform -> SGPR
#pragma unroll
        for (int k = 0; k < 16; ++k) acc = fmaf(pv[k], w[oc * 16 + k], acc);   // uniform -> SGPR
        o[oc * 16384] = fmaxf(acc, 0.f);
    }
}

// ---------------- conv2: 16->16, 128->64 ----------------
__global__ __launch_bounds__(256, 2) void conv2_k(const float* __restrict__ in, const float* __restrict__ w,
                                                  const float* __restrict__ bias, float* __restrict__ out) {
    int idx = blockIdx.x * 256 + threadIdx.x;   // 64*64*64
    int ox = idx & 63;
    int oy = (idx >> 6) & 63;
    int b  = idx >> 12;
    const float* xin = in + (size_t)b * (16 * 16384);
    float acc[16];
#pragma unroll
    for (int oc = 0; oc < 16; ++oc) acc[oc] = bias[oc];     // uniform
    for (int ic = 0; ic < 16; ++ic) {
        const float* xc = xin + ic * 16384;
        float p[16];
#pragma unroll
        for (int ky = 0; ky < 4; ++ky) {
            int iy = 2 * oy - 1 + ky;
#pragma unroll
            for (int kx = 0; kx < 4; ++kx) {
                int ix = 2 * ox - 1 + kx;
                p[ky * 4 + kx] = (iy >= 0 && iy < 128 && ix >= 0 && ix < 128)
                                     ? xc[iy * 128 + ix] : 0.f;
            }
        }
        const float* wp0 = w + ic * 16;             // (oc,ic,4,4): oc stride 256
#pragma unroll
        for (int oc = 0; oc < 16; ++oc) {
            const float* wp = wp0 + oc * 256;       // uniform
#pragma unroll
            for (int k = 0; k < 16; ++k) acc[oc] = fmaf(p[k], wp[k], acc[oc]);
        }
    }
    float* o = out + (size_t)b * (16 * 4096) + oy * 64 + ox;
#pragma unroll
    for (int oc = 0; oc < 16; ++oc) o[oc * 4096] = fmaxf(acc[oc], 0.f);
}

// ---------------- residual block: out = in + relu(conv3x3(in)), (64,16,64,64) ----------------
__global__ __launch_bounds__(256, 2) void res_k(const float* __restrict__ in, const float* __restrict__ w,
                                                const float* __restrict__ bias, float* __restrict__ out) {
    int b    = blockIdx.x >> 3;            // image
    int ty   = (blockIdx.x & 7) * 8;       // tile row origin (8 rows/block)
    int row  = threadIdx.x >> 5;           // 0..7
    int col2 = threadIdx.x & 31;           // 0..31
    int oy   = ty + row;
    int ox0  = col2 * 2;
    const float* xin = in + (size_t)b * 65536;
    float acc0[16], acc1[16];
#pragma unroll
    for (int oc = 0; oc < 16; ++oc) { acc0[oc] = bias[oc]; acc1[oc] = bias[oc]; }
    for (int ic = 0; ic < 16; ++ic) {
        const float* xc = xin + ic * 4096;
        float p[3][4];
#pragma unroll
        for (int r = 0; r < 3; ++r) {
            int iy = oy - 1 + r;
            bool yok = (iy >= 0 && iy < 64);
#pragma unroll
            for (int c = 0; c < 4; ++c) {
                int ix = ox0 - 1 + c;
                p[r][c] = (yok && ix >= 0 && ix < 64) ? xc[iy * 64 + ix] : 0.f;
            }
        }
        const float* wp0 = w + ic * 9;              // (oc,ic,3,3): oc stride 144
#pragma unroll
        for (int oc = 0; oc < 16; ++oc) {
            const float* wp = wp0 + oc * 144;       // uniform
#pragma unroll
            for (int r = 0; r < 3; ++r) {
#pragma unroll
                for (int k = 0; k < 3; ++k) {
                    float wv = wp[r * 3 + k];
                    acc0[oc] = fmaf(p[r][k],     wv, acc0[oc]);
                    acc1[oc] = fmaf(p[r][k + 1], wv, acc1[oc]);
                }
            }
        }
    }
    float* o        = out + (size_t)b * 65536 + oy * 64 + ox0;
    const float* rr = xin + oy * 64 + ox0;
#pragma unroll
    for (int oc = 0; oc < 16; ++oc) {
        float2 rv = *(const float2*)(rr + oc * 4096);
        float2 ov;
        ov.x = rv.x + fmaxf(acc0[oc], 0.f);
        ov.y = rv.y + fmaxf(acc1[oc], 0.f);
        *(float2*)(o + oc * 4096) = ov;
    }
}

// ---------------- VQ: rows of 16 contiguous floats (raw NCHW flatten), K=64 ----------------
__global__ __launch_bounds__(256) void vq_k(const float* __restrict__ h, const float* __restrict__ cb,
                                            float* __restrict__ q, float* __restrict__ idx_out) {
    __shared__ float cbs[1024];  // 64 x 16
    __shared__ float cn[64];
    for (int i = threadIdx.x; i < 1024; i += 256) cbs[i] = cb[i];
    __syncthreads();
    if (threadIdx.x < 64) {
        float s = 0.f;
#pragma unroll
        for (int d = 0; d < 16; ++d) { float v = cbs[threadIdx.x * 16 + d]; s = fmaf(v, v, s); }
        cn[threadIdx.x] = s;
    }
    __syncthreads();
    int r = blockIdx.x * 256 + threadIdx.x;   // 262144 rows
    float f[16];
    const float4* hp = (const float4*)(h + (size_t)r * 16);
#pragma unroll
    for (int j = 0; j < 4; ++j) {
        float4 v = hp[j];
        f[j * 4 + 0] = v.x; f[j * 4 + 1] = v.y; f[j * 4 + 2] = v.z; f[j * 4 + 3] = v.w;
    }
    float best = 3.4e38f;
    int bi = 0;
    for (int k = 0; k < 64; ++k) {
        float dot = 0.f;
#pragma unroll
        for (int d = 0; d < 16; ++d) dot = fmaf(f[d], cbs[k * 16 + d], dot);
        float dist = cn[k] - 2.f * dot;   // +||f||^2 is per-row constant, argmin-invariant
        if (dist < best) { best = dist; bi = k; }
    }
    float4* qp = (float4*)(q + (size_t)r * 16);
    const float4* cp = (const float4*)(cbs + bi * 16);
#pragma unroll
    for (int j = 0; j < 4; ++j) qp[j] = cp[j];
    idx_out[r] = (float)bi;
}

// ---------------- tconv1: ConvTranspose2d 16->16, k4 s2 p1, 64->128, relu ----------------
// Row-pair: outer dy (compile-time), acc[2][16]; parity-literal weight idx -> SGPR; zero LDS;
// channel-last coalesced 128B/lane stores. launch_bounds(256,2) raises VGPR budget (no spill).
__global__ __launch_bounds__(256, 2) void tconv1_k(const float* __restrict__ in,
                                                   const float* __restrict__ w1, const float* __restrict__ b1,
                                                   float* __restrict__ out) {
    int idx = blockIdx.x * 256 + threadIdx.x;   // 64 img * 64*64 quads
    int v = idx & 63;                            // quad col (output cols 2v, 2v+1)
    int u = (idx >> 6) & 63;                     // quad row
    int b = idx >> 12;
    const float* xin = in + (size_t)b * 65536;   // (16,64,64) channel-first

#pragma unroll
    for (int dy = 0; dy < 2; ++dy) {
        float acc[2][16];                        // [dx][oc] -- 32 regs
#pragma unroll
        for (int dx = 0; dx < 2; ++dx)
#pragma unroll
            for (int oc = 0; oc < 16; ++oc) acc[dx][oc] = b1[oc];   // uniform

        for (int ic = 0; ic < 16; ++ic) {
            const float* xc = xin + ic * 4096;
            float pv[2][3];
#pragma unroll
            for (int r = 0; r < 2; ++r) {
                int jy = u + dy - 1 + r;
                bool yok = (jy >= 0 && jy < 64);
#pragma unroll
                for (int c3 = 0; c3 < 3; ++c3) {
                    int jx = v - 1 + c3;
                    pv[r][c3] = (yok && jx >= 0 && jx < 64) ? xc[jy * 64 + jx] : 0.f;
                }
            }
            const float* wic = w1 + ic * 256;    // (ic,oc,4,4)
#pragma unroll
            for (int dx = 0; dx < 2; ++dx) {
#pragma unroll
                for (int a = 0; a < 2; ++a) {
                    int ky = (1 - dy) + 2 * a;   // literal
                    int r  = 1 - a;
#pragma unroll
                    for (int c = 0; c < 2; ++c) {
                        int kx = (1 - dx) + 2 * c;   // literal
                        int c3 = dx - c + 1;
                        float p = pv[r][c3];
#pragma unroll
                        for (int oc = 0; oc < 16; ++oc)
                            acc[dx][oc] = fmaf(p, wic[oc * 16 + ky * 4 + kx], acc[dx][oc]);
                    }
                }
            }
        }
        int my = 2 * u + dy;
        float4* o = (float4*)(out + (((size_t)b * 16384) + my * 128 + 2 * v) * 16);
#pragma unroll
        for (int dx = 0; dx < 2; ++dx) {
#pragma unroll
            for (int j = 0; j < 4; ++j) {
                float4 t;
                t.x = fmaxf(acc[dx][j * 4 + 0], 0.f);
                t.y = fmaxf(acc[dx][j * 4 + 1], 0.f);
                t.z = fmaxf(acc[dx][j * 4 + 2], 0.f);
                t.w = fmaxf(acc[dx][j * 4 + 3], 0.f);
                o[dx * 4 + j] = t;
            }
        }
    }
}

// ---------------- tconv2: ConvTranspose2d 16->1, k4 s2 p1, 128->256 ----------------
// 32x32 output tile/block; stage 18x18x16 channel-last slab into LDS [324][20]; float4 LDS reads.
#define P2 20
__global__ __launch_bounds__(256) void tconv2_k(const float* __restrict__ f1,
                                                const float* __restrict__ w2, const float* __restrict__ b2,
                                                float* __restrict__ out) {
    __shared__ float s1[324 * P2];       // [pixel(18x18)][16 ch + pad4]
    __shared__ float ws2[256];           // (ic,1,4,4)
    __shared__ float b2s;
    if (threadIdx.x < 256) ws2[threadIdx.x] = w2[threadIdx.x];
    if (threadIdx.x == 0) b2s = b2[0];

    int tile = blockIdx.x & 63;
    int b    = blockIdx.x >> 6;
    int Y0 = (tile >> 3) * 32;           // final-out tile origin (256x256)
    int X0 = (tile & 7) * 32;
    int m0 = (Y0 >> 1) - 1;              // halo origin in tconv1-out coords [-1,128]
    int n0 = (X0 >> 1) - 1;
    const float* fb = f1 + (size_t)b * 262144;   // (128,128,16) channel-last

    for (int i = threadIdx.x; i < 5184; i += 256) {
        int p  = i >> 4;
        int ic = i & 15;
        int my = m0 + p / 18;
        int mx = n0 + p % 18;
        float v = 0.f;
        if (my >= 0 && my < 128 && mx >= 0 && mx < 128)
            v = fb[((size_t)(my * 128 + mx)) * 16 + ic];
        s1[p * P2 + ic] = v;
    }
    __syncthreads();

    int ly0 = threadIdx.x >> 5;          // 0..7
    int lx  = threadIdx.x & 31;
    int gx  = X0 + lx;
    int kyb = (Y0 + ly0 + 1) & 1;
    int kxb = (gx + 1) & 1;
    float wr[2][2][16];
#pragma unroll
    for (int a = 0; a < 2; ++a) {
#pragma unroll
        for (int c = 0; c < 2; ++c) {
            int ky = kyb + 2 * a, kx = kxb + 2 * c;
#pragma unroll
            for (int ic = 0; ic < 16; ++ic)
                wr[a][c][ic] = ws2[ic * 16 + ky * 4 + kx];
        }
    }
    int sx[2];
#pragma unroll
    for (int c = 0; c < 2; ++c) sx[c] = ((gx + 1 - (kxb + 2 * c)) >> 1) - n0;

#pragma unroll
    for (int r = 0; r < 4; ++r) {
        int gy = Y0 + ly0 + 8 * r;
        float acc = b2s;
#pragma unroll
        for (int a = 0; a < 2; ++a) {
            int sy = ((gy + 1 - (kyb + 2 * a)) >> 1) - m0;
#pragma unroll
            for (int c = 0; c < 2; ++c) {
                const float4* sp4 = (const float4*)&s1[(sy * 18 + sx[c]) * P2];
#pragma unroll
                for (int j = 0; j < 4; ++j) {
                    float4 v = sp4[j];
                    acc = fmaf(v.x, wr[a][c][j * 4 + 0], acc);
                    acc = fmaf(v.y, wr[a][c][j * 4 + 1], acc);
                    acc = fmaf(v.z, wr[a][c][j * 4 + 2], acc);
                    acc = fmaf(v.w, wr[a][c][j * 4 + 3], acc);
                }
            }
        }
        out[(size_t)b * 65536 + gy * 256 + gx] = acc;
    }
}

extern "C" void kernel_launch(void* const* d_in, const int* in_sizes, int n_in,
                              void* d_out, int out_size, void* d_ws, size_t ws_size,
                              hipStream_t stream) {
    const float* x    = (const float*)d_in[0];
    const float* c1w  = (const float*)d_in[1];
    const float* c1b  = (const float*)d_in[2];
    const float* c2w  = (const float*)d_in[3];
    const float* c2b  = (const float*)d_in[4];
    const float* er1w = (const float*)d_in[5];
    const float* er1b = (const float*)d_in[6];
    const float* er2w = (const float*)d_in[7];
    const float* er2b = (const float*)d_in[8];
    const float* cb   = (const float*)d_in[9];
    const float* dr1w = (const float*)d_in[10];
    const float* dr1b = (const float*)d_in[11];
    const float* dr2w = (const float*)d_in[12];
    const float* dr2b = (const float*)d_in[13];
    const float* t1w  = (const float*)d_in[14];
    const float* t1b  = (const float*)d_in[15];
    const float* t2w  = (const float*)d_in[16];
    const float* t2b  = (const float*)d_in[17];

    float* f1 = (float*)d_ws;                                // 64 MiB: dec ch-last
    float* f2 = (float*)((char*)d_ws + 67108864);            // (64,16,64,64)
    float* f3 = (float*)((char*)d_ws + 67108864 + 16777216); // (64,16,64,64)

    float* out     = (float*)d_out;                          // decoded: 4,194,304 f32
    float* idx_out = out + 4194304;                          // indices: 262,144 f32

    conv1_k <<<4096, 256, 0, stream>>>(x, c1w, c1b, f1);
    conv2_k <<<1024, 256, 0, stream>>>(f1, c2w, c2b, f2);
    res_k   <<< 512, 256, 0, stream>>>(f2, er1w, er1b, f3);  // er1
    res_k   <<< 512, 256, 0, stream>>>(f3, er2w, er2b, f2);  // er2
    vq_k    <<<1024, 256, 0, stream>>>(f2, cb, f3, idx_out); // quantized -> f3
    res_k   <<< 512, 256, 0, stream>>>(f3, dr1w, dr1b, f2);  // dr1
    res_k   <<< 512, 256, 0, stream>>>(f2, dr2w, dr2b, f3);  // dr2
    tconv1_k<<<1024, 256, 0, stream>>>(f3, t1w, t1b, f1);
    tconv2_k<<<4096, 256, 0, stream>>>(f1, t2w, t2b, out);
}